// Round 1
// baseline (141.249 us; speedup 1.0000x reference)
//
#include <hip/hip_runtime.h>

// Problem constants (match reference): 256x256 image, 512 gaussians.
constexpr int IMG_H = 256;
constexpr int IMG_W = 256;
constexpr int MAXN  = 512;

// Per-gaussian record in workspace, 16 floats (64 B, float4-aligned), depth-sorted:
// [0..3]  x_min, x_max, y_min, y_max   (bbox, float, same semantics as ref)
// [4..7]  mx, my, inv00, inv01
// [8..11] inv11, opac, col_r, col_g
// [12]    col_b   [13..15] pad

__global__ void preprocess_kernel(
    const float* __restrict__ positions,
    const float* __restrict__ cov3d,
    const float* __restrict__ opacities,
    const float* __restrict__ colors,
    const float* __restrict__ Km,
    const float* __restrict__ Rm,
    const float* __restrict__ tv,
    float* __restrict__ ws,
    int N)
{
    __shared__ float sz[MAXN];
    const int i = threadIdx.x;   // launched with blockDim.x == N, one block

    // Camera params (uniform; L1-broadcast)
    const float R00 = Rm[0], R01 = Rm[1], R02 = Rm[2];
    const float R10 = Rm[3], R11 = Rm[4], R12 = Rm[5];
    const float R20 = Rm[6], R21 = Rm[7], R22 = Rm[8];
    const float t0 = tv[0], t1 = tv[1], t2 = tv[2];
    const float K00 = Km[0], K01 = Km[1], K02 = Km[2];
    const float K10 = Km[3], K11 = Km[4], K12 = Km[5];
    const float K20 = Km[6], K21 = Km[7], K22 = Km[8];

    const float px = positions[i*3+0];
    const float py = positions[i*3+1];
    const float pz = positions[i*3+2];

    // means_cam = R*p + t
    const float cx = R00*px + R01*py + R02*pz + t0;
    const float cy = R10*px + R11*py + R12*pz + t1;
    const float cz = R20*px + R21*py + R22*pz + t2;

    // proj = K*cam ; means_2d = proj.xy / proj.z
    const float pr0 = K00*cx + K01*cy + K02*cz;
    const float pr1 = K10*cx + K11*cy + K12*cz;
    const float pr2 = K20*cx + K21*cy + K22*cz;
    const float mx = pr0 / pr2;
    const float my = pr1 / pr2;

    // Jacobian rows: j0 = (fx/z, 0, -fx*cx/z^2), j1 = (0, fy/z, -fy*cy/z^2), z = cz
    const float fx = K00, fy = K11;
    const float invz  = 1.0f / cz;
    const float invz2 = invz * invz;
    const float j00 =  fx * invz;
    const float j02 = -fx * cx * invz2;
    const float j11 =  fy * invz;
    const float j12 = -fy * cy * invz2;

    // C = cov3d[i]
    const float C00 = cov3d[i*9+0], C01 = cov3d[i*9+1], C02 = cov3d[i*9+2];
    const float C10 = cov3d[i*9+3], C11 = cov3d[i*9+4], C12 = cov3d[i*9+5];
    const float C20 = cov3d[i*9+6], C21 = cov3d[i*9+7], C22 = cov3d[i*9+8];

    // T1 = R * C
    const float T100 = R00*C00 + R01*C10 + R02*C20;
    const float T101 = R00*C01 + R01*C11 + R02*C21;
    const float T102 = R00*C02 + R01*C12 + R02*C22;
    const float T110 = R10*C00 + R11*C10 + R12*C20;
    const float T111 = R10*C01 + R11*C11 + R12*C21;
    const float T112 = R10*C02 + R11*C12 + R12*C22;
    const float T120 = R20*C00 + R21*C10 + R22*C20;
    const float T121 = R20*C01 + R21*C11 + R22*C21;
    const float T122 = R20*C02 + R21*C12 + R22*C22;
    // M = T1 * R^T  (cov in camera frame, symmetric)
    const float M00 = T100*R00 + T101*R01 + T102*R02;
    const float M01 = T100*R10 + T101*R11 + T102*R12;
    const float M02 = T100*R20 + T101*R21 + T102*R22;
    const float M11 = T110*R10 + T111*R11 + T112*R12;
    const float M12 = T110*R20 + T111*R21 + T112*R22;
    const float M20 = T120*R00 + T121*R01 + T122*R02;
    const float M21 = T120*R10 + T121*R11 + T122*R12;
    const float M22 = T120*R20 + T121*R21 + T122*R22;

    // cov2d = J M J^T + 0.3 I
    const float v00 = M00*j00 + M02*j02;        // (M j0)[0]
    const float v02 = M20*j00 + M22*j02;        // (M j0)[2]
    const float v10 = M01*j11 + M02*j12;        // (M j1)[0]
    const float v11 = M11*j11 + M12*j12;        // (M j1)[1]
    const float v12 = M21*j11 + M22*j12;        // (M j1)[2]

    const float va = j00*v00 + j02*v02 + 0.3f;  // cov2d[0][0]
    const float vb = j00*v10 + j02*v12;         // cov2d[0][1]
    const float vc = j11*v11 + j12*v12 + 0.3f;  // cov2d[1][1]

    const float det  = fmaxf(va*vc - vb*vb, 1e-8f);
    const float idet = 1.0f / det;
    const float inv00 =  vc * idet;
    const float inv01 = -vb * idet;
    const float inv11 =  va * idet;

    const float half_diff = (va - vc) * 0.5f;
    const float disc = fmaxf(half_diff*half_diff + vb*vb, 1e-8f);
    const float max_eig = (va + vc) * 0.5f + sqrtf(disc);
    const float radii = 3.0f * sqrtf(max_eig);

    const float x_min = fmaxf(0.0f, truncf(mx - radii));
    const float x_max = fminf((float)IMG_W, truncf(mx + radii) + 1.0f);
    const float y_min = fmaxf(0.0f, truncf(my - radii));
    const float y_max = fminf((float)IMG_H, truncf(my + radii) + 1.0f);

    // Stable rank sort by depth (matches jnp.argsort ascending, stable ties)
    sz[i] = cz;
    __syncthreads();
    int rank = 0;
    for (int j = 0; j < N; ++j) {
        const float zj = sz[j];
        rank += (zj < cz || (zj == cz && j < i)) ? 1 : 0;
    }

    float* o = ws + rank * 16;
    o[0]  = x_min; o[1]  = x_max; o[2]  = y_min; o[3]  = y_max;
    o[4]  = mx;    o[5]  = my;    o[6]  = inv00; o[7]  = inv01;
    o[8]  = inv11; o[9]  = opacities[i];
    o[10] = colors[i*3+0]; o[11] = colors[i*3+1]; o[12] = colors[i*3+2];
    o[13] = 0.0f;  o[14] = 0.0f;  o[15] = 0.0f;
}

__global__ __launch_bounds__(256) void raster_kernel(
    const float* __restrict__ ws, float* __restrict__ out, int N)
{
    __shared__ float4 sg[MAXN * 4];   // 32 KB: all gaussian records
    const int tid = threadIdx.y * 16 + threadIdx.x;
    const float4* __restrict__ src = (const float4*)ws;
    for (int k = tid; k < N * 4; k += 256) sg[k] = src[k];
    __syncthreads();

    const int x = blockIdx.x * 16 + threadIdx.x;
    const int y = blockIdx.y * 16 + threadIdx.y;
    const float fxp = (float)x;
    const float fyp = (float)y;

    float T = 1.0f, accr = 0.0f, accg = 0.0f, accb = 0.0f;
    for (int g = 0; g < N; ++g) {
        const float4 bb = sg[g*4+0];   // LDS broadcast (same addr all lanes)
        if (fxp >= bb.x && fxp < bb.y && fyp >= bb.z && fyp < bb.w) {
            const float4 p1 = sg[g*4+1];
            const float4 p2 = sg[g*4+2];
            const float4 p3 = sg[g*4+3];
            const float dx = fxp - p1.x;
            const float dy = fyp - p1.y;
            const float mahal = p1.z*dx*dx + 2.0f*p1.w*dx*dy + p2.x*dy*dy;
            const float a = p2.y * __expf(-0.5f * mahal);
            const float w = T * a;
            accr += w * p2.z;
            accg += w * p2.w;
            accb += w * p3.x;
            T *= (1.0f - a);
        }
    }
    const int pix = (y * IMG_W + x) * 3;
    out[pix + 0] = accr;
    out[pix + 1] = accg;
    out[pix + 2] = accb;
}

extern "C" void kernel_launch(void* const* d_in, const int* in_sizes, int n_in,
                              void* d_out, int out_size, void* d_ws, size_t ws_size,
                              hipStream_t stream)
{
    const float* positions = (const float*)d_in[0];
    const float* cov3d     = (const float*)d_in[1];
    const float* opacities = (const float*)d_in[2];
    const float* colors    = (const float*)d_in[3];
    const float* Km        = (const float*)d_in[4];
    const float* Rm        = (const float*)d_in[5];
    const float* tv        = (const float*)d_in[6];
    float* ws  = (float*)d_ws;
    float* out = (float*)d_out;
    const int N = in_sizes[0] / 3;   // 512

    preprocess_kernel<<<dim3(1), dim3(N), 0, stream>>>(
        positions, cov3d, opacities, colors, Km, Rm, tv, ws, N);

    dim3 block(16, 16);
    dim3 grid(IMG_W / 16, IMG_H / 16);
    raster_kernel<<<grid, block, 0, stream>>>(ws, out, N);
}

// Round 2
// 89.972 us; speedup vs baseline: 1.5699x; 1.5699x over previous
//
#include <hip/hip_runtime.h>

// Problem constants (match reference): 256x256 image, 512 gaussians.
constexpr int IMG_H = 256;
constexpr int IMG_W = 256;
constexpr int MAXN  = 512;

// Per-gaussian record in workspace, 16 floats (64 B), depth-sorted:
// rec[0] = {x_min, x_max, y_min, y_max}
// rec[1] = {mx, my, h00, h01}      h00 = -0.5*inv00, h01 = -inv01
// rec[2] = {h11, opac, col_r, col_g}  h11 = -0.5*inv11
// rec[3] = {col_b, 0, 0, 0}

__global__ __launch_bounds__(MAXN) void preprocess_kernel(
    const float* __restrict__ positions,
    const float* __restrict__ cov3d,
    const float* __restrict__ opacities,
    const float* __restrict__ colors,
    const float* __restrict__ Km,
    const float* __restrict__ Rm,
    const float* __restrict__ tv,
    float* __restrict__ ws,
    int N)
{
    __shared__ float sz[MAXN];
    const int i = threadIdx.x;   // one block, blockDim.x == N

    const float R00 = Rm[0], R01 = Rm[1], R02 = Rm[2];
    const float R10 = Rm[3], R11 = Rm[4], R12 = Rm[5];
    const float R20 = Rm[6], R21 = Rm[7], R22 = Rm[8];
    const float t0 = tv[0], t1 = tv[1], t2 = tv[2];
    const float K00 = Km[0], K01 = Km[1], K02 = Km[2];
    const float K10 = Km[3], K11 = Km[4], K12 = Km[5];
    const float K20 = Km[6], K21 = Km[7], K22 = Km[8];

    const float px = positions[i*3+0];
    const float py = positions[i*3+1];
    const float pz = positions[i*3+2];

    const float cx = R00*px + R01*py + R02*pz + t0;
    const float cy = R10*px + R11*py + R12*pz + t1;
    const float cz = R20*px + R21*py + R22*pz + t2;

    const float pr0 = K00*cx + K01*cy + K02*cz;
    const float pr1 = K10*cx + K11*cy + K12*cz;
    const float pr2 = K20*cx + K21*cy + K22*cz;
    const float mx = pr0 / pr2;
    const float my = pr1 / pr2;

    const float fx = K00, fy = K11;
    const float invz  = 1.0f / cz;
    const float invz2 = invz * invz;
    const float j00 =  fx * invz;
    const float j02 = -fx * cx * invz2;
    const float j11 =  fy * invz;
    const float j12 = -fy * cy * invz2;

    const float C00 = cov3d[i*9+0], C01 = cov3d[i*9+1], C02 = cov3d[i*9+2];
    const float C10 = cov3d[i*9+3], C11 = cov3d[i*9+4], C12 = cov3d[i*9+5];
    const float C20 = cov3d[i*9+6], C21 = cov3d[i*9+7], C22 = cov3d[i*9+8];

    const float T100 = R00*C00 + R01*C10 + R02*C20;
    const float T101 = R00*C01 + R01*C11 + R02*C21;
    const float T102 = R00*C02 + R01*C12 + R02*C22;
    const float T110 = R10*C00 + R11*C10 + R12*C20;
    const float T111 = R10*C01 + R11*C11 + R12*C21;
    const float T112 = R10*C02 + R11*C12 + R12*C22;
    const float T120 = R20*C00 + R21*C10 + R22*C20;
    const float T121 = R20*C01 + R21*C11 + R22*C21;
    const float T122 = R20*C02 + R21*C12 + R22*C22;
    const float M00 = T100*R00 + T101*R01 + T102*R02;
    const float M01 = T100*R10 + T101*R11 + T102*R12;
    const float M02 = T100*R20 + T101*R21 + T102*R22;
    const float M11 = T110*R10 + T111*R11 + T112*R12;
    const float M12 = T110*R20 + T111*R21 + T112*R22;
    const float M20 = T120*R00 + T121*R01 + T122*R02;
    const float M21 = T120*R10 + T121*R11 + T122*R12;
    const float M22 = T120*R20 + T121*R21 + T122*R22;

    const float v00 = M00*j00 + M02*j02;
    const float v02 = M20*j00 + M22*j02;
    const float v10 = M01*j11 + M02*j12;
    const float v11 = M11*j11 + M12*j12;
    const float v12 = M21*j11 + M22*j12;

    const float va = j00*v00 + j02*v02 + 0.3f;
    const float vb = j00*v10 + j02*v12;
    const float vc = j11*v11 + j12*v12 + 0.3f;

    const float det  = fmaxf(va*vc - vb*vb, 1e-8f);
    const float idet = 1.0f / det;
    const float inv00 =  vc * idet;
    const float inv01 = -vb * idet;
    const float inv11 =  va * idet;

    const float half_diff = (va - vc) * 0.5f;
    const float disc = fmaxf(half_diff*half_diff + vb*vb, 1e-8f);
    const float max_eig = (va + vc) * 0.5f + sqrtf(disc);
    const float radii = 3.0f * sqrtf(max_eig);

    const float x_min = fmaxf(0.0f, truncf(mx - radii));
    const float x_max = fminf((float)IMG_W, truncf(mx + radii) + 1.0f);
    const float y_min = fmaxf(0.0f, truncf(my - radii));
    const float y_max = fminf((float)IMG_H, truncf(my + radii) + 1.0f);

    // Stable rank sort by depth (matches jnp.argsort ascending, stable ties).
    // float4-unrolled: 128 iterations with 4-way ILP instead of 512 serial LDS reads.
    sz[i] = cz;
    __syncthreads();
    int rank = 0;
    for (int j = 0; j < N; j += 4) {
        const float4 z4 = *(const float4*)&sz[j];
        rank += (z4.x < cz || (z4.x == cz && (j+0) < i)) ? 1 : 0;
        rank += (z4.y < cz || (z4.y == cz && (j+1) < i)) ? 1 : 0;
        rank += (z4.z < cz || (z4.z == cz && (j+2) < i)) ? 1 : 0;
        rank += (z4.w < cz || (z4.w == cz && (j+3) < i)) ? 1 : 0;
    }

    float4* o = (float4*)(ws + rank * 16);
    o[0] = make_float4(x_min, x_max, y_min, y_max);
    o[1] = make_float4(mx, my, -0.5f*inv00, -inv01);
    o[2] = make_float4(-0.5f*inv11, opacities[i], colors[i*3+0], colors[i*3+1]);
    o[3] = make_float4(colors[i*3+2], 0.0f, 0.0f, 0.0f);
}

// 16x8 pixel tiles, 128 threads (2 waves), 512 blocks.
constexpr int TW = 16;
constexpr int TH = 8;

__global__ __launch_bounds__(TW*TH) void raster_kernel(
    const float* __restrict__ ws, float* __restrict__ out, int N)
{
    __shared__ float4 s_rec[MAXN * 4];            // 32 KB, compacted culled records
    __shared__ int s_list[MAXN];                  // 2 KB
    __shared__ unsigned long long s_mask[8];
    __shared__ int s_cnt[8];
    __shared__ int s_total;

    const int tid  = threadIdx.y * TW + threadIdx.x;   // 0..127
    const int lane = tid & 63;
    const int wv   = tid >> 6;                         // 0..1
    const float4* __restrict__ rec = (const float4*)ws;

    const float tx0 = (float)(blockIdx.x * TW);
    const float ty0 = (float)(blockIdx.y * TH);

    // --- Tile culling: order-preserving ballot compaction over 8 segments of 64 ---
    for (int s = wv; s < 8; s += 2) {
        const int g = s * 64 + lane;
        const float4 bb = rec[g * 4];   // {x_min, x_max, y_min, y_max}
        const bool hit = (bb.x < tx0 + (float)TW) && (bb.y > tx0) &&
                         (bb.z < ty0 + (float)TH) && (bb.w > ty0);
        const unsigned long long m = __ballot(hit);
        if (lane == 0) { s_mask[s] = m; s_cnt[s] = __popcll(m); }
    }
    __syncthreads();
    for (int s = wv; s < 8; s += 2) {
        int base = 0;
        #pragma unroll
        for (int q = 0; q < 8; ++q) base += (q < s) ? s_cnt[q] : 0;
        const unsigned long long m = s_mask[s];
        if ((m >> lane) & 1ull) {
            const int pos = base + __popcll(m & ((1ull << lane) - 1ull));
            s_list[pos] = s * 64 + lane;
        }
    }
    if (tid == 0) {
        int t = 0;
        #pragma unroll
        for (int q = 0; q < 8; ++q) t += s_cnt[q];
        s_total = t;
    }
    __syncthreads();
    const int K = s_total;

    // --- Stage only the culled records into LDS (depth order preserved) ---
    for (int k = tid; k < K; k += TW * TH) {
        const float4* r = rec + s_list[k] * 4;
        s_rec[k*4+0] = r[0];
        s_rec[k*4+1] = r[1];
        s_rec[k*4+2] = r[2];
        s_rec[k*4+3] = r[3];
    }
    __syncthreads();

    const int x = blockIdx.x * TW + threadIdx.x;
    const int y = blockIdx.y * TH + threadIdx.y;
    const float fxp = (float)x;
    const float fyp = (float)y;

    // --- Branchless front-to-back compositing over culled list ---
    float T = 1.0f, accr = 0.0f, accg = 0.0f, accb = 0.0f;
    #pragma unroll 4
    for (int k = 0; k < K; ++k) {
        const float4 bb = s_rec[k*4+0];   // LDS broadcast reads
        const float4 p1 = s_rec[k*4+1];
        const float4 p2 = s_rec[k*4+2];
        const float  cb = s_rec[k*4+3].x;
        const bool in = (fxp >= bb.x) & (fxp < bb.y) & (fyp >= bb.z) & (fyp < bb.w);
        const float dx = fxp - p1.x;
        const float dy = fyp - p1.y;
        // exp(-0.5*mahal) with signs folded into h00/h01/h11 at preprocess
        const float e = p1.z*dx*dx + p1.w*dx*dy + p2.x*dy*dy;
        const float a = in ? p2.y * __expf(e) : 0.0f;
        const float w = T * a;
        accr = fmaf(w, p2.z, accr);
        accg = fmaf(w, p2.w, accg);
        accb = fmaf(w, cb, accb);
        T *= (1.0f - a);
    }

    const int pix = (y * IMG_W + x) * 3;
    out[pix + 0] = accr;
    out[pix + 1] = accg;
    out[pix + 2] = accb;
}

extern "C" void kernel_launch(void* const* d_in, const int* in_sizes, int n_in,
                              void* d_out, int out_size, void* d_ws, size_t ws_size,
                              hipStream_t stream)
{
    const float* positions = (const float*)d_in[0];
    const float* cov3d     = (const float*)d_in[1];
    const float* opacities = (const float*)d_in[2];
    const float* colors    = (const float*)d_in[3];
    const float* Km        = (const float*)d_in[4];
    const float* Rm        = (const float*)d_in[5];
    const float* tv        = (const float*)d_in[6];
    float* ws  = (float*)d_ws;
    float* out = (float*)d_out;
    const int N = in_sizes[0] / 3;   // 512

    preprocess_kernel<<<dim3(1), dim3(N), 0, stream>>>(
        positions, cov3d, opacities, colors, Km, Rm, tv, ws, N);

    dim3 block(TW, TH);
    dim3 grid(IMG_W / TW, IMG_H / TH);
    raster_kernel<<<grid, block, 0, stream>>>(ws, out, N);
}

// Round 3
// 79.683 us; speedup vs baseline: 1.7726x; 1.1291x over previous
//
#include <hip/hip_runtime.h>

// Fully fused gaussian rasterizer: every block redundantly preprocesses all
// 512 gaussians (parallel across its 128 threads), culls to its 16x8 tile,
// sorts the survivors by (z, original index) — identical order to the
// reference's stable argsort restricted to the subset — and composites.
// No global intermediate (d_ws untouched), single kernel launch.

constexpr int IMG_H = 256;
constexpr int IMG_W = 256;
constexpr int MAXN  = 512;
constexpr int TW    = 16;
constexpr int TH    = 8;
constexpr int NTHR  = TW * TH;   // 128 threads, 2 waves

__global__ __launch_bounds__(NTHR) void fused_raster_kernel(
    const float* __restrict__ positions,
    const float* __restrict__ cov3d,
    const float* __restrict__ opacities,
    const float* __restrict__ colors,
    const float* __restrict__ Km,
    const float* __restrict__ Rm,
    const float* __restrict__ tv,
    float* __restrict__ out)
{
    // Record per gaussian (AoS, 4x float4 = 64 B):
    // [0] = {x_min, x_max, y_min, y_max}
    // [1] = {mx, my, h00, h01}   h00 = -0.5*inv00, h01 = -inv01
    // [2] = {h11, opac, col_r, col_g}
    // [3] = {col_b, 0, 0, 0}
    __shared__ float4 s_all[MAXN * 4];            // 32 KB, indexed by original g
    __shared__ float  s_z[MAXN];                  // 2 KB
    __shared__ int    s_list[MAXN];               // 2 KB (culled, pre-sort)
    __shared__ int    s_order[MAXN];              // 2 KB (culled, depth-sorted g)
    __shared__ unsigned long long s_mask[8];
    __shared__ int    s_cnt[8];
    __shared__ int    s_total;

    const int tid  = threadIdx.y * TW + threadIdx.x;  // 0..127
    const int lane = tid & 63;
    const int wv   = tid >> 6;                        // 0..1

    const float tx0 = (float)(blockIdx.x * TW);
    const float ty0 = (float)(blockIdx.y * TH);

    // Camera params (wave-uniform scalar loads)
    const float R00 = Rm[0], R01 = Rm[1], R02 = Rm[2];
    const float R10 = Rm[3], R11 = Rm[4], R12 = Rm[5];
    const float R20 = Rm[6], R21 = Rm[7], R22 = Rm[8];
    const float t0 = tv[0], t1 = tv[1], t2 = tv[2];
    const float K00 = Km[0], K01 = Km[1], K02 = Km[2];
    const float K10 = Km[3], K11 = Km[4], K12 = Km[5];
    const float K20 = Km[6], K21 = Km[7], K22 = Km[8];
    const float fx = K00, fy = K11;

    // --- Phase 1: preprocess 4 gaussians/thread; g = k*128 + tid keeps
    //     wave-lane <-> ballot-segment alignment exact (seg = 2k + wv). ---
    #pragma unroll
    for (int k = 0; k < 4; ++k) {
        const int g = k * NTHR + tid;

        const float px = positions[g*3+0];
        const float py = positions[g*3+1];
        const float pz = positions[g*3+2];

        const float cx = R00*px + R01*py + R02*pz + t0;
        const float cy = R10*px + R11*py + R12*pz + t1;
        const float cz = R20*px + R21*py + R22*pz + t2;

        const float pr0 = K00*cx + K01*cy + K02*cz;
        const float pr1 = K10*cx + K11*cy + K12*cz;
        const float pr2 = K20*cx + K21*cy + K22*cz;
        const float mx = pr0 / pr2;
        const float my = pr1 / pr2;

        const float invz  = 1.0f / cz;
        const float invz2 = invz * invz;
        const float j00 =  fx * invz;
        const float j02 = -fx * cx * invz2;
        const float j11 =  fy * invz;
        const float j12 = -fy * cy * invz2;

        const float C00 = cov3d[g*9+0], C01 = cov3d[g*9+1], C02 = cov3d[g*9+2];
        const float C10 = cov3d[g*9+3], C11 = cov3d[g*9+4], C12 = cov3d[g*9+5];
        const float C20 = cov3d[g*9+6], C21 = cov3d[g*9+7], C22 = cov3d[g*9+8];

        const float T100 = R00*C00 + R01*C10 + R02*C20;
        const float T101 = R00*C01 + R01*C11 + R02*C21;
        const float T102 = R00*C02 + R01*C12 + R02*C22;
        const float T110 = R10*C00 + R11*C10 + R12*C20;
        const float T111 = R10*C01 + R11*C11 + R12*C21;
        const float T112 = R10*C02 + R11*C12 + R12*C22;
        const float T120 = R20*C00 + R21*C10 + R22*C20;
        const float T121 = R20*C01 + R21*C11 + R22*C21;
        const float T122 = R20*C02 + R21*C12 + R22*C22;
        const float M00 = T100*R00 + T101*R01 + T102*R02;
        const float M01 = T100*R10 + T101*R11 + T102*R12;
        const float M02 = T100*R20 + T101*R21 + T102*R22;
        const float M11 = T110*R10 + T111*R11 + T112*R12;
        const float M12 = T110*R20 + T111*R21 + T112*R22;
        const float M20 = T120*R00 + T121*R01 + T122*R02;
        const float M21 = T120*R10 + T121*R11 + T122*R12;
        const float M22 = T120*R20 + T121*R21 + T122*R22;

        const float v00 = M00*j00 + M02*j02;
        const float v02 = M20*j00 + M22*j02;
        const float v10 = M01*j11 + M02*j12;
        const float v11 = M11*j11 + M12*j12;
        const float v12 = M21*j11 + M22*j12;

        const float va = j00*v00 + j02*v02 + 0.3f;
        const float vb = j00*v10 + j02*v12;
        const float vc = j11*v11 + j12*v12 + 0.3f;

        const float det  = fmaxf(va*vc - vb*vb, 1e-8f);
        const float idet = 1.0f / det;
        const float inv00 =  vc * idet;
        const float inv01 = -vb * idet;
        const float inv11 =  va * idet;

        const float half_diff = (va - vc) * 0.5f;
        const float disc = fmaxf(half_diff*half_diff + vb*vb, 1e-8f);
        const float max_eig = (va + vc) * 0.5f + sqrtf(disc);
        const float radii = 3.0f * sqrtf(max_eig);

        const float x_min = fmaxf(0.0f, truncf(mx - radii));
        const float x_max = fminf((float)IMG_W, truncf(mx + radii) + 1.0f);
        const float y_min = fmaxf(0.0f, truncf(my - radii));
        const float y_max = fminf((float)IMG_H, truncf(my + radii) + 1.0f);

        s_all[g*4+0] = make_float4(x_min, x_max, y_min, y_max);
        s_all[g*4+1] = make_float4(mx, my, -0.5f*inv00, -inv01);
        s_all[g*4+2] = make_float4(-0.5f*inv11, opacities[g],
                                   colors[g*3+0], colors[g*3+1]);
        s_all[g*4+3] = make_float4(colors[g*3+2], 0.0f, 0.0f, 0.0f);
        s_z[g] = cz;

        // Tile cull on in-register bbox; ballot bit position == lane == g%64.
        const bool hit = (x_min < tx0 + (float)TW) && (x_max > tx0) &&
                         (y_min < ty0 + (float)TH) && (y_max > ty0);
        const unsigned long long m = __ballot(hit);
        if (lane == 0) {
            const int seg = 2*k + wv;   // == g/64 for this wave's lanes
            s_mask[seg] = m;
            s_cnt[seg]  = __popcll(m);
        }
    }
    __syncthreads();

    // --- Phase 2: order-preserving compaction into s_list ---
    #pragma unroll
    for (int k = 0; k < 4; ++k) {
        const int seg = 2*k + wv;
        int base = 0;
        #pragma unroll
        for (int q = 0; q < 8; ++q) base += (q < seg) ? s_cnt[q] : 0;
        const unsigned long long m = s_mask[seg];
        if ((m >> lane) & 1ull) {
            const int pos = base + __popcll(m & ((1ull << lane) - 1ull));
            s_list[pos] = seg * 64 + lane;
        }
    }
    if (tid == 0) {
        int t = 0;
        #pragma unroll
        for (int q = 0; q < 8; ++q) t += s_cnt[q];
        s_total = t;
    }
    __syncthreads();
    const int K = s_total;

    // --- Phase 3: rank-sort survivors by (z, g) — matches stable argsort
    //     order of the reference restricted to the culled subset. ---
    for (int m = tid; m < K; m += NTHR) {
        const int   g  = s_list[m];
        const float zg = s_z[g];
        int rank = 0;
        for (int j = 0; j < K; ++j) {        // wave-uniform j -> LDS broadcasts
            const int   gj = s_list[j];
            const float zj = s_z[gj];
            rank += (zj < zg || (zj == zg && gj < g)) ? 1 : 0;
        }
        s_order[rank] = g;
    }
    __syncthreads();

    // --- Phase 4: front-to-back compositing over sorted survivors ---
    const int x = blockIdx.x * TW + threadIdx.x;
    const int y = blockIdx.y * TH + threadIdx.y;
    const float fxp = (float)x;
    const float fyp = (float)y;

    float T = 1.0f, accr = 0.0f, accg = 0.0f, accb = 0.0f;
    for (int m = 0; m < K; ++m) {
        const int g = s_order[m];            // broadcast
        const float4 bb = s_all[g*4+0];      // broadcasts (same addr all lanes)
        const float4 p1 = s_all[g*4+1];
        const float4 p2 = s_all[g*4+2];
        const float  cb = s_all[g*4+3].x;
        const bool in = (fxp >= bb.x) & (fxp < bb.y) & (fyp >= bb.z) & (fyp < bb.w);
        const float dx = fxp - p1.x;
        const float dy = fyp - p1.y;
        const float e = p1.z*dx*dx + p1.w*dx*dy + p2.x*dy*dy;
        const float a = in ? p2.y * __expf(e) : 0.0f;
        const float w = T * a;
        accr = fmaf(w, p2.z, accr);
        accg = fmaf(w, p2.w, accg);
        accb = fmaf(w, cb, accb);
        T *= (1.0f - a);
    }

    const int pix = (y * IMG_W + x) * 3;
    out[pix + 0] = accr;
    out[pix + 1] = accg;
    out[pix + 2] = accb;
}

extern "C" void kernel_launch(void* const* d_in, const int* in_sizes, int n_in,
                              void* d_out, int out_size, void* d_ws, size_t ws_size,
                              hipStream_t stream)
{
    const float* positions = (const float*)d_in[0];
    const float* cov3d     = (const float*)d_in[1];
    const float* opacities = (const float*)d_in[2];
    const float* colors    = (const float*)d_in[3];
    const float* Km        = (const float*)d_in[4];
    const float* Rm        = (const float*)d_in[5];
    const float* tv        = (const float*)d_in[6];
    float* out = (float*)d_out;

    dim3 block(TW, TH);
    dim3 grid(IMG_W / TW, IMG_H / TH);
    fused_raster_kernel<<<grid, block, 0, stream>>>(
        positions, cov3d, opacities, colors, Km, Rm, tv, out);
}

// Round 4
// 78.994 us; speedup vs baseline: 1.7881x; 1.0087x over previous
//
#include <hip/hip_runtime.h>

// Fully fused gaussian rasterizer: every block redundantly preprocesses all
// 512 gaussians (2 per thread across 256 threads), culls to its 16x16 tile,
// sorts survivors by (z, original index) — identical to the reference's
// stable argsort restricted to the subset — then composites front-to-back.
// Single kernel, no global intermediate. Grid = 256 blocks = 1 per CU.

constexpr int IMG_H = 256;
constexpr int IMG_W = 256;
constexpr int MAXN  = 512;
constexpr int TW    = 16;
constexpr int TH    = 16;
constexpr int NTHR  = TW * TH;   // 256 threads, 4 waves

__global__ __launch_bounds__(NTHR) void fused_raster_kernel(
    const float* __restrict__ positions,
    const float* __restrict__ cov3d,
    const float* __restrict__ opacities,
    const float* __restrict__ colors,
    const float* __restrict__ Km,
    const float* __restrict__ Rm,
    const float* __restrict__ tv,
    float* __restrict__ out)
{
    // Record per gaussian (AoS, 4x float4 = 64 B), indexed by original g:
    // [0] = {x_min, x_max, y_min, y_max}
    // [1] = {mx, my, h00, h01}   h00 = -0.5*inv00, h01 = -inv01
    // [2] = {h11, opac, col_r, col_g}   h11 = -0.5*inv11
    // [3] = {col_b, 0, 0, 0}
    __shared__ float4 s_all[MAXN * 4];            // 32 KB
    __shared__ float  s_z[MAXN];                  // 2 KB
    __shared__ int    s_list[MAXN];               // 2 KB (culled, pre-sort)
    __shared__ int    s_order[MAXN];              // 2 KB (culled, depth-sorted)
    __shared__ unsigned long long s_mask[8];
    __shared__ int    s_cnt[8];
    __shared__ int    s_total;

    const int tid  = threadIdx.y * TW + threadIdx.x;  // 0..255
    const int lane = tid & 63;
    const int wv   = tid >> 6;                        // 0..3

    const float tx0 = (float)(blockIdx.x * TW);
    const float ty0 = (float)(blockIdx.y * TH);

    const float R00 = Rm[0], R01 = Rm[1], R02 = Rm[2];
    const float R10 = Rm[3], R11 = Rm[4], R12 = Rm[5];
    const float R20 = Rm[6], R21 = Rm[7], R22 = Rm[8];
    const float t0 = tv[0], t1 = tv[1], t2 = tv[2];
    const float K00 = Km[0], K01 = Km[1], K02 = Km[2];
    const float K10 = Km[3], K11 = Km[4], K12 = Km[5];
    const float K20 = Km[6], K21 = Km[7], K22 = Km[8];
    const float fx = K00, fy = K11;

    // --- Phase 1: preprocess 2 gaussians/thread; g = k*256 + tid keeps
    //     wave-lane <-> ballot-segment alignment exact (seg = 4k + wv). ---
    #pragma unroll
    for (int k = 0; k < 2; ++k) {
        const int g = k * NTHR + tid;

        const float px = positions[g*3+0];
        const float py = positions[g*3+1];
        const float pz = positions[g*3+2];

        const float cx = R00*px + R01*py + R02*pz + t0;
        const float cy = R10*px + R11*py + R12*pz + t1;
        const float cz = R20*px + R21*py + R22*pz + t2;

        const float pr0 = K00*cx + K01*cy + K02*cz;
        const float pr1 = K10*cx + K11*cy + K12*cz;
        const float pr2 = K20*cx + K21*cy + K22*cz;
        const float mx = pr0 / pr2;
        const float my = pr1 / pr2;

        const float invz  = 1.0f / cz;
        const float invz2 = invz * invz;
        const float j00 =  fx * invz;
        const float j02 = -fx * cx * invz2;
        const float j11 =  fy * invz;
        const float j12 = -fy * cy * invz2;

        const float C00 = cov3d[g*9+0], C01 = cov3d[g*9+1], C02 = cov3d[g*9+2];
        const float C10 = cov3d[g*9+3], C11 = cov3d[g*9+4], C12 = cov3d[g*9+5];
        const float C20 = cov3d[g*9+6], C21 = cov3d[g*9+7], C22 = cov3d[g*9+8];

        const float T100 = R00*C00 + R01*C10 + R02*C20;
        const float T101 = R00*C01 + R01*C11 + R02*C21;
        const float T102 = R00*C02 + R01*C12 + R02*C22;
        const float T110 = R10*C00 + R11*C10 + R12*C20;
        const float T111 = R10*C01 + R11*C11 + R12*C21;
        const float T112 = R10*C02 + R11*C12 + R12*C22;
        const float T120 = R20*C00 + R21*C10 + R22*C20;
        const float T121 = R20*C01 + R21*C11 + R22*C21;
        const float T122 = R20*C02 + R21*C12 + R22*C22;
        const float M00 = T100*R00 + T101*R01 + T102*R02;
        const float M01 = T100*R10 + T101*R11 + T102*R12;
        const float M02 = T100*R20 + T101*R21 + T102*R22;
        const float M11 = T110*R10 + T111*R11 + T112*R12;
        const float M12 = T110*R20 + T111*R21 + T112*R22;
        const float M20 = T120*R00 + T121*R01 + T122*R02;
        const float M21 = T120*R10 + T121*R11 + T122*R12;
        const float M22 = T120*R20 + T121*R21 + T122*R22;

        const float v00 = M00*j00 + M02*j02;
        const float v02 = M20*j00 + M22*j02;
        const float v10 = M01*j11 + M02*j12;
        const float v11 = M11*j11 + M12*j12;
        const float v12 = M21*j11 + M22*j12;

        const float va = j00*v00 + j02*v02 + 0.3f;
        const float vb = j00*v10 + j02*v12;
        const float vc = j11*v11 + j12*v12 + 0.3f;

        const float det  = fmaxf(va*vc - vb*vb, 1e-8f);
        const float idet = 1.0f / det;
        const float inv00 =  vc * idet;
        const float inv01 = -vb * idet;
        const float inv11 =  va * idet;

        const float half_diff = (va - vc) * 0.5f;
        const float disc = fmaxf(half_diff*half_diff + vb*vb, 1e-8f);
        const float max_eig = (va + vc) * 0.5f + sqrtf(disc);
        const float radii = 3.0f * sqrtf(max_eig);

        const float x_min = fmaxf(0.0f, truncf(mx - radii));
        const float x_max = fminf((float)IMG_W, truncf(mx + radii) + 1.0f);
        const float y_min = fmaxf(0.0f, truncf(my - radii));
        const float y_max = fminf((float)IMG_H, truncf(my + radii) + 1.0f);

        s_all[g*4+0] = make_float4(x_min, x_max, y_min, y_max);
        s_all[g*4+1] = make_float4(mx, my, -0.5f*inv00, -inv01);
        s_all[g*4+2] = make_float4(-0.5f*inv11, opacities[g],
                                   colors[g*3+0], colors[g*3+1]);
        s_all[g*4+3] = make_float4(colors[g*3+2], 0.0f, 0.0f, 0.0f);
        s_z[g] = cz;

        // Tile cull on in-register bbox; ballot bit position == lane == g%64.
        const bool hit = (x_min < tx0 + (float)TW) && (x_max > tx0) &&
                         (y_min < ty0 + (float)TH) && (y_max > ty0);
        const unsigned long long m = __ballot(hit);
        if (lane == 0) {
            const int seg = 4*k + wv;   // == g/64 for this wave's lanes
            s_mask[seg] = m;
            s_cnt[seg]  = __popcll(m);
        }
    }
    __syncthreads();

    // --- Phase 2: order-preserving compaction into s_list ---
    #pragma unroll
    for (int k = 0; k < 2; ++k) {
        const int seg = 4*k + wv;
        int base = 0;
        #pragma unroll
        for (int q = 0; q < 8; ++q) base += (q < seg) ? s_cnt[q] : 0;
        const unsigned long long m = s_mask[seg];
        if ((m >> lane) & 1ull) {
            const int pos = base + __popcll(m & ((1ull << lane) - 1ull));
            s_list[pos] = seg * 64 + lane;
        }
    }
    if (tid == 0) {
        int t = 0;
        #pragma unroll
        for (int q = 0; q < 8; ++q) t += s_cnt[q];
        s_total = t;
    }
    __syncthreads();
    const int K = s_total;

    // --- Phase 3: rank-sort survivors by (z, g) — matches stable argsort
    //     order of the reference restricted to the culled subset. ---
    for (int m = tid; m < K; m += NTHR) {
        const int   g  = s_list[m];
        const float zg = s_z[g];
        int rank = 0;
        for (int j = 0; j < K; ++j) {        // wave-uniform j -> LDS broadcasts
            const int   gj = s_list[j];
            const float zj = s_z[gj];
            rank += (zj < zg || (zj == zg && gj < g)) ? 1 : 0;
        }
        s_order[rank] = g;
    }
    __syncthreads();

    // --- Phase 4: front-to-back compositing over sorted survivors ---
    const int x = blockIdx.x * TW + threadIdx.x;
    const int y = blockIdx.y * TH + threadIdx.y;
    const float fxp = (float)x;
    const float fyp = (float)y;

    float T = 1.0f, accr = 0.0f, accg = 0.0f, accb = 0.0f;
    for (int m = 0; m < K; ++m) {
        const int g = s_order[m];            // broadcast
        const float4 bb = s_all[g*4+0];      // broadcasts (same addr all lanes)
        const float4 p1 = s_all[g*4+1];
        const float4 p2 = s_all[g*4+2];
        const float  cb = s_all[g*4+3].x;
        const bool in = (fxp >= bb.x) & (fxp < bb.y) & (fyp >= bb.z) & (fyp < bb.w);
        const float dx = fxp - p1.x;
        const float dy = fyp - p1.y;
        const float e = p1.z*dx*dx + p1.w*dx*dy + p2.x*dy*dy;
        const float a = in ? p2.y * __expf(e) : 0.0f;
        const float w = T * a;
        accr = fmaf(w, p2.z, accr);
        accg = fmaf(w, p2.w, accg);
        accb = fmaf(w, cb, accb);
        T *= (1.0f - a);
    }

    const int pix = (y * IMG_W + x) * 3;
    out[pix + 0] = accr;
    out[pix + 1] = accg;
    out[pix + 2] = accb;
}

extern "C" void kernel_launch(void* const* d_in, const int* in_sizes, int n_in,
                              void* d_out, int out_size, void* d_ws, size_t ws_size,
                              hipStream_t stream)
{
    const float* positions = (const float*)d_in[0];
    const float* cov3d     = (const float*)d_in[1];
    const float* opacities = (const float*)d_in[2];
    const float* colors    = (const float*)d_in[3];
    const float* Km        = (const float*)d_in[4];
    const float* Rm        = (const float*)d_in[5];
    const float* tv        = (const float*)d_in[6];
    float* out = (float*)d_out;

    dim3 block(TW, TH);
    dim3 grid(IMG_W / TW, IMG_H / TH);
    fused_raster_kernel<<<grid, block, 0, stream>>>(
        positions, cov3d, opacities, colors, Km, Rm, tv, out);
}